// Round 1
// baseline (89.727 us; speedup 1.0000x reference)
//
#include <hip/hip_runtime.h>
#include <cstdint>

#define T_STEPS 2048
#define NFEAT   2048
#define A_POS 0.05f
#define A_NEG 0.05f
#define LR    0.01f
#define DECAY 0.60653065971263342f   // exp(-1/2), tau_pos == tau_neg == 2

typedef unsigned short u16;
typedef short short8 __attribute__((ext_vector_type(8)));
typedef float f32x4 __attribute__((ext_vector_type(4)));

__device__ __forceinline__ uint32_t f2bf(float f) {
  uint32_t u = __float_as_uint(f);
  return (u + 0x7FFFu + ((u >> 16) & 1u)) >> 16;   // RNE, finite values only
}
__device__ __forceinline__ uint32_t packbf2(float lo, float hi) {
  return f2bf(lo) | (f2bf(hi) << 16);
}

// ---------------------------------------------------------------------------
// Kernel 1: kinT[j][t] = a_pos*F[t][j] - a_neg*B[t][j]  (bf16, transposed)
// F/B are forward/backward exponential scans of in[t][j]; chunked over t with
// a 64-step halo (decay^64 = e^-32, negligible).
// ---------------------------------------------------------------------------
#define TC   64
#define HALO 64
__global__ __launch_bounds__(256) void scan_kin_kernel(
    const float* __restrict__ in, u16* __restrict__ kinT) {
  const int j  = blockIdx.x * 256 + threadIdx.x;
  const int t0 = blockIdx.y * TC;
  const float d = DECAY;

  float kv[TC];
  float f = 0.f;
  int tb = t0 - HALO; if (tb < 0) tb = 0;
  for (int t = tb; t < t0; ++t) f = d * (f + in[(size_t)t * NFEAT + j]);
#pragma unroll
  for (int u = 0; u < TC; ++u) {
    kv[u] = f;                                   // F[t0+u] (excludes in[t0+u])
    f = d * (f + in[(size_t)(t0 + u) * NFEAT + j]);
  }

  float b = 0.f;
  int te = t0 + TC - 1 + HALO; if (te > T_STEPS - 1) te = T_STEPS - 1;
  for (int t = te; t >= t0 + TC; --t) b = in[(size_t)t * NFEAT + j] + d * b;
#pragma unroll
  for (int u = TC - 1; u >= 0; --u) {
    b = in[(size_t)(t0 + u) * NFEAT + j] + d * b;  // B[t0+u] (includes t)
    kv[u] = A_POS * kv[u] - A_NEG * b;
  }

  uint4* dst = (uint4*)&kinT[(size_t)j * T_STEPS + t0];
#pragma unroll
  for (int g = 0; g < TC / 8; ++g) {
    uint4 w;
    w.x = packbf2(kv[8 * g + 0], kv[8 * g + 1]);
    w.y = packbf2(kv[8 * g + 2], kv[8 * g + 3]);
    w.z = packbf2(kv[8 * g + 4], kv[8 * g + 5]);
    w.w = packbf2(kv[8 * g + 6], kv[8 * g + 7]);
    dst[g] = w;
  }
}

// ---------------------------------------------------------------------------
// Kernel 2: outT[i][t] = bf16(out[t][i])  — tiled LDS transpose + convert
// ---------------------------------------------------------------------------
__global__ __launch_bounds__(256) void transpose_bf16_kernel(
    const float* __restrict__ src, u16* __restrict__ dstT) {
  __shared__ float tile[64][65];
  const int t0 = blockIdx.x * 64;
  const int i0 = blockIdx.y * 64;
#pragma unroll
  for (int p = 0; p < 16; ++p) {
    int idx = threadIdx.x + p * 256;
    int r = idx >> 6, c = idx & 63;
    tile[r][c] = src[(size_t)(t0 + r) * NFEAT + i0 + c];
  }
  __syncthreads();
#pragma unroll
  for (int p = 0; p < 8; ++p) {
    int idx = threadIdx.x + p * 256;
    int pr = idx >> 5, pc = idx & 31;
    uint32_t w = packbf2(tile[2 * pc][pr], tile[2 * pc + 1][pr]);
    ((uint32_t*)dstT)[(size_t)(i0 + pr) * (T_STEPS / 2) + (t0 >> 1) + pc] = w;
  }
}

// ---------------------------------------------------------------------------
// Kernel 3: C[i][j] = W[i][j] + LR * sum_k A[i][k]*B[j][k]
// A = outT [2048][2048] bf16, B = kinT [2048][2048] bf16 (both K-contiguous).
// 128x128 tile, BK=32, 4 waves (2x2), 16x16x32 MFMA, global_load_lds dbuf.
// ---------------------------------------------------------------------------
__global__ __launch_bounds__(256) void stdp_gemm_kernel(
    const u16* __restrict__ A, const u16* __restrict__ B,
    const float* __restrict__ W, float* __restrict__ C) {
  __shared__ u16 ldsA[2][128 * 32];
  __shared__ u16 ldsB[2][128 * 32];
  const int tid = threadIdx.x;
  const int lane = tid & 63, wave = tid >> 6;
  const int wm = wave >> 1, wn = wave & 1;
  const int i0 = blockIdx.y * 128, j0 = blockIdx.x * 128;
  const int lr = lane & 15, lk = lane >> 4;

  f32x4 acc[4][4];
#pragma unroll
  for (int m = 0; m < 4; ++m)
#pragma unroll
    for (int n = 0; n < 4; ++n) acc[m][n] = (f32x4){0.f, 0.f, 0.f, 0.f};

  auto stage = [&](int buf, int kt) {
    const int k0 = kt * 32;
#pragma unroll
    for (int h = 0; h < 2; ++h) {
      int chunk = h * 256 + tid;
      int r = chunk >> 2, c = chunk & 3;
      __builtin_amdgcn_global_load_lds(
          (const __attribute__((address_space(1))) void*)(A + (size_t)(i0 + r) * T_STEPS + k0 + c * 8),
          (__attribute__((address_space(3))) void*)((char*)&ldsA[buf][0] + (h * 256 + wave * 64) * 16),
          16, 0, 0);
      __builtin_amdgcn_global_load_lds(
          (const __attribute__((address_space(1))) void*)(B + (size_t)(j0 + r) * T_STEPS + k0 + c * 8),
          (__attribute__((address_space(3))) void*)((char*)&ldsB[buf][0] + (h * 256 + wave * 64) * 16),
          16, 0, 0);
    }
  };

  stage(0, 0);
  asm volatile("s_waitcnt vmcnt(0)" ::: "memory");
  __syncthreads();

  int cur = 0;
  for (int kt = 0; kt < T_STEPS / 32; ++kt) {
    if (kt + 1 < T_STEPS / 32) stage(cur ^ 1, kt + 1);  // prefetch next tile
    short8 af[4], bfr[4];
#pragma unroll
    for (int m = 0; m < 4; ++m)
      af[m] = *(const short8*)&ldsA[cur][(wm * 64 + m * 16 + lr) * 32 + lk * 8];
#pragma unroll
    for (int n = 0; n < 4; ++n)
      bfr[n] = *(const short8*)&ldsB[cur][(wn * 64 + n * 16 + lr) * 32 + lk * 8];
#pragma unroll
    for (int m = 0; m < 4; ++m)
#pragma unroll
      for (int n = 0; n < 4; ++n)
        acc[m][n] = __builtin_amdgcn_mfma_f32_16x16x32_bf16(af[m], bfr[n], acc[m][n], 0, 0, 0);
    __syncthreads();  // drains vmcnt(0)+lgkmcnt(0): prefetch landed, reads done
    cur ^= 1;
  }

  // epilogue: C = W + LR * acc   (C/D layout: col=lane&15, row=(lane>>4)*4+r)
#pragma unroll
  for (int m = 0; m < 4; ++m)
#pragma unroll
    for (int n = 0; n < 4; ++n) {
      int col = j0 + wn * 64 + n * 16 + lr;
#pragma unroll
      for (int r = 0; r < 4; ++r) {
        int row = i0 + wm * 64 + m * 16 + lk * 4 + r;
        size_t off = (size_t)row * NFEAT + col;
        C[off] = W[off] + LR * acc[m][n][r];
      }
    }
}

extern "C" void kernel_launch(void* const* d_in, const int* in_sizes, int n_in,
                              void* d_out, int out_size, void* d_ws, size_t ws_size,
                              hipStream_t stream) {
  const float* weight  = (const float*)d_in[0];
  const float* in_spk  = (const float*)d_in[1];
  const float* out_spk = (const float*)d_in[2];
  float* out = (float*)d_out;

  u16* kinT = (u16*)d_ws;                                   // 8 MB bf16 [I][T]
  u16* outT = (u16*)d_ws + (size_t)T_STEPS * NFEAT;         // 8 MB bf16 [O][T]

  dim3 g1(NFEAT / 256, T_STEPS / TC);
  scan_kin_kernel<<<g1, 256, 0, stream>>>(in_spk, kinT);

  dim3 g2(T_STEPS / 64, NFEAT / 64);
  transpose_bf16_kernel<<<g2, 256, 0, stream>>>(out_spk, outT);

  dim3 g3(NFEAT / 128, NFEAT / 128);
  stdp_gemm_kernel<<<g3, 256, 0, stream>>>(outT, kinT, weight, out);
}